// Round 1
// baseline (2773.934 us; speedup 1.0000x reference)
//
#include <hip/hip_runtime.h>
#include <math.h>

#define DIM 256
#define KCODES 8192
#define BN_TOTAL 32768

// ---------------- kernel 1: codebook squared norms ----------------
__global__ __launch_bounds__(256) void vq_c2(const float* __restrict__ cb,
                                             float* __restrict__ c2) {
  int g = blockIdx.x * 256 + threadIdx.x;
  int code = g >> 6;
  int lane = g & 63;
  float4 v = *(const float4*)(cb + code * DIM + lane * 4);
  float s = v.x * v.x + v.y * v.y + v.z * v.z + v.w * v.w;
#pragma unroll
  for (int m = 32; m >= 1; m >>= 1) s += __shfl_xor(s, m, 64);
  if (lane == 0) c2[code] = s;
}

// ---------------- kernel 2: fused distance + argmin ----------------
// block: 256 threads (tx 0..15, ty 0..15). Tile: 64 rows x 128 codes.
// A (x rows) resident in LDS [64][260]; B (codebook) streamed [128][20] in
// 16-d chunks with register prefetch pipeline.
__global__ __launch_bounds__(256, 2)
void vq_main(const float* __restrict__ x, const float* __restrict__ cb,
             const float* __restrict__ c2g, int* __restrict__ out_ind) {
  __shared__ float As[64][260];
  __shared__ float Bs[128][20];
  const int t = threadIdx.x;
  const int tx = t & 15;
  const int ty = t >> 4;
  const int row0 = blockIdx.x * 64;

  // Load A tile: 64x256 floats, 16 float4 per thread, fully coalesced.
#pragma unroll
  for (int c = 0; c < 16; ++c) {
    int flat = c * 1024 + t * 4;
    int r = flat >> 8;
    int col = flat & 255;
    *(float4*)(&As[r][col]) = *(const float4*)(x + (row0 + r) * DIM + col);
  }

  float best[4];
  int besti[4];
#pragma unroll
  for (int i = 0; i < 4; ++i) { best[i] = INFINITY; besti[i] = 0; }

  // Prologue: prefetch chunk 0 (ktile 0, d0 0) into registers.
  float4 pf0, pf1;
  {
    int flat = t * 4;
    int cl = flat >> 4, col = flat & 15;
    pf0 = *(const float4*)(cb + cl * DIM + col);
    flat = 1024 + t * 4;
    cl = flat >> 4; col = flat & 15;
    pf1 = *(const float4*)(cb + cl * DIM + col);
  }

  int cc = 0;  // global chunk counter: kt*16 + dch, 1024 total
#pragma unroll 1
  for (int kt = 0; kt < 64; ++kt) {
    float acc[4][8];
#pragma unroll
    for (int i = 0; i < 4; ++i)
#pragma unroll
      for (int j = 0; j < 8; ++j) acc[i][j] = 0.0f;

#pragma unroll 1
    for (int dch = 0; dch < 16; ++dch) {
      __syncthreads();  // previous compute done (also covers As on iter 0)
      {
        int flat = t * 4;
        int cl = flat >> 4, col = flat & 15;
        *(float4*)(&Bs[cl][col]) = pf0;
        flat = 1024 + t * 4;
        cl = flat >> 4; col = flat & 15;
        *(float4*)(&Bs[cl][col]) = pf1;
      }
      __syncthreads();
      // Prefetch next chunk while computing this one.
      int nc = cc + 1;
      if (nc < 1024) {
        int nkt = nc >> 4;
        int nd0 = (nc & 15) << 4;
        int flat = t * 4;
        int cl = flat >> 4, col = flat & 15;
        pf0 = *(const float4*)(cb + (nkt * 128 + cl) * DIM + nd0 + col);
        flat = 1024 + t * 4;
        cl = flat >> 4; col = flat & 15;
        pf1 = *(const float4*)(cb + (nkt * 128 + cl) * DIM + nd0 + col);
      }
      const int d0 = dch << 4;
#pragma unroll
      for (int dd = 0; dd < 16; dd += 4) {
        float4 a[4], b[8];
#pragma unroll
        for (int i = 0; i < 4; ++i)
          a[i] = *(const float4*)(&As[i * 16 + ty][d0 + dd]);
#pragma unroll
        for (int j = 0; j < 8; ++j)
          b[j] = *(const float4*)(&Bs[j * 16 + tx][dd]);
#pragma unroll
        for (int i = 0; i < 4; ++i)
#pragma unroll
          for (int j = 0; j < 8; ++j) {
            acc[i][j] = fmaf(a[i].x, b[j].x, acc[i][j]);
            acc[i][j] = fmaf(a[i].y, b[j].y, acc[i][j]);
            acc[i][j] = fmaf(a[i].z, b[j].z, acc[i][j]);
            acc[i][j] = fmaf(a[i].w, b[j].w, acc[i][j]);
          }
      }
      ++cc;
    }
    // Tile epilogue: score = ||c||^2 - 2*dot (||x||^2 dropped: row-constant).
#pragma unroll
    for (int j = 0; j < 8; ++j) {
      int code = kt * 128 + j * 16 + tx;
      float cv = c2g[code];
#pragma unroll
      for (int i = 0; i < 4; ++i) {
        float s = cv - 2.0f * acc[i][j];
        if (s < best[i]) { best[i] = s; besti[i] = code; }  // strict <: first min
      }
    }
  }

  // Cross-lane reduce over the 16 tx threads sharing each row; tie -> lower idx.
#pragma unroll
  for (int i = 0; i < 4; ++i) {
    float v = best[i];
    int idx = besti[i];
#pragma unroll
    for (int m = 8; m >= 1; m >>= 1) {
      float vo = __shfl_xor(v, m, 64);
      int io = __shfl_xor(idx, m, 64);
      if (vo < v || (vo == v && io < idx)) { v = vo; idx = io; }
    }
    if (tx == 0) out_ind[row0 + i * 16 + ty] = idx;
  }
}

// ---------------- kernel 3: gather + loss + scatter stats ----------------
// One wave per row.
__global__ __launch_bounds__(256)
void vq_epi(const float* __restrict__ x, const float* __restrict__ cb,
            const int* __restrict__ ind, float* __restrict__ out_q,
            float* __restrict__ out_ind, float* __restrict__ out_loss,
            float* __restrict__ out_cs, float* __restrict__ out_es) {
  int wid = threadIdx.x >> 6;
  int lane = threadIdx.x & 63;
  int row = blockIdx.x * 4 + wid;
  int k = ind[row];
  const float4 q = *(const float4*)(cb + k * DIM + lane * 4);
  const float4 xv = *(const float4*)(x + row * DIM + lane * 4);
  *(float4*)(out_q + row * DIM + lane * 4) = q;
  float dx = q.x - xv.x, dy = q.y - xv.y, dz = q.z - xv.z, dw = q.w - xv.w;
  float s = dx * dx + dy * dy + dz * dz + dw * dw;
#pragma unroll
  for (int m = 32; m >= 1; m >>= 1) s += __shfl_xor(s, m, 64);
  if (lane == 0) {
    atomicAdd(out_loss, s * (1.0f / 8388608.0f));
    atomicAdd(out_cs + k, 1.0f);
    out_ind[row] = (float)k;
  }
  atomicAdd(out_es + k * DIM + lane * 4 + 0, xv.x);
  atomicAdd(out_es + k * DIM + lane * 4 + 1, xv.y);
  atomicAdd(out_es + k * DIM + lane * 4 + 2, xv.z);
  atomicAdd(out_es + k * DIM + lane * 4 + 3, xv.w);
}

extern "C" void kernel_launch(void* const* d_in, const int* in_sizes, int n_in,
                              void* d_out, int out_size, void* d_ws,
                              size_t ws_size, hipStream_t stream) {
  const float* x = (const float*)d_in[0];
  const float* cb = (const float*)d_in[1];
  float* out = (float*)d_out;
  // Flat f32 output layout in reference return order:
  float* out_q = out;                   // 8,388,608
  float* out_ind = out + 8388608;       // 32,768
  float* out_loss = out + 8421376;      // 1
  float* out_cs = out + 8421377;        // 8,192
  float* out_es = out + 8429569;        // 2,097,152
  float* c2 = (float*)d_ws;                         // 8192 f32
  int* ind = (int*)((char*)d_ws + KCODES * 4);      // 32768 i32

  // Zero the atomic-accumulated region every launch (harness doesn't re-poison).
  hipMemsetAsync(out_loss, 0, (size_t)(1 + KCODES + KCODES * DIM) * sizeof(float),
                 stream);

  vq_c2<<<KCODES / 4, 256, 0, stream>>>(cb, c2);
  vq_main<<<BN_TOTAL / 64, 256, 0, stream>>>(x, cb, c2, ind);
  vq_epi<<<BN_TOTAL / 4, 256, 0, stream>>>(x, cb, ind, out_q, out_ind, out_loss,
                                           out_cs, out_es);
}

// Round 4
// 948.128 us; speedup vs baseline: 2.9257x; 2.9257x over previous
//
#include <hip/hip_runtime.h>
#include <hip/hip_bf16.h>
#include <math.h>

#define DIM 256
#define KCODES 8192
#define BN_TOTAL 32768
#define NSPLIT 4
#define BKW 512     // stored split width: [hi(256) | lo(256)]
// logical GEMM K = 768: region0 x_hi*c_hi, region1 x_hi*c_lo, region2 x_lo*c_hi

// d_out flat f32 layout (reference return order)
#define OUT_IND 8388608
#define OUT_LOSS 8421376
#define OUT_CS 8421377
#define OUT_ES 8429569
#define OUT_TOTAL 10526721

typedef unsigned short u16;
typedef unsigned int u32;
typedef __attribute__((ext_vector_type(8))) short bf16x8;
typedef __attribute__((ext_vector_type(4))) float f32x4;
typedef __attribute__((address_space(1))) const void gvoid_t;
typedef __attribute__((address_space(3))) void lvoid_t;

__device__ __forceinline__ void split2(float v, u16& hi, u16& lo) {
  __hip_bfloat16 h = __float2bfloat16(v);
  float hf = __bfloat162float(h);
  __hip_bfloat16 l = __float2bfloat16(v - hf);
  hi = *reinterpret_cast<u16*>(&h);
  lo = *reinterpret_cast<u16*>(&l);
}

// merge two lex-sorted top2 pairs
__device__ __forceinline__ void merge2(float& a1, int& b1, float& a2, int& b2,
                                       float w1, int j1, float w2, int j2) {
  bool less = (w1 < a1) || (w1 == a1 && j1 < b1);
  float t1v = less ? w1 : a1; int t1i = less ? j1 : b1;
  float ov  = less ? a1 : w1; int oi  = less ? b1 : j1;
  float sv  = less ? w2 : a2; int si  = less ? j2 : b2;
  bool less2 = (sv < ov) || (sv == ov && si < oi);
  a1 = t1v; b1 = t1i;
  a2 = less2 ? sv : ov; b2 = less2 ? si : oi;
}

// ---------------- prep: split x into [hi|lo] bf16, stride 512 --------------
__global__ __launch_bounds__(256) void vq_split_x(const float* __restrict__ x,
                                                  u16* __restrict__ A) {
  int g = blockIdx.x * 256 + threadIdx.x;   // 32768*32
  int row = g >> 5;
  int d0 = (g & 31) * 8;
  float4 v0 = *(const float4*)(x + (size_t)row * DIM + d0);
  float4 v1 = *(const float4*)(x + (size_t)row * DIM + d0 + 4);
  float vv[8] = {v0.x, v0.y, v0.z, v0.w, v1.x, v1.y, v1.z, v1.w};
  u16 h[8], l[8];
#pragma unroll
  for (int i = 0; i < 8; ++i) split2(vv[i], h[i], l[i]);
  uint4 hv, lv;
  hv.x = (u32)h[0] | ((u32)h[1] << 16); hv.y = (u32)h[2] | ((u32)h[3] << 16);
  hv.z = (u32)h[4] | ((u32)h[5] << 16); hv.w = (u32)h[6] | ((u32)h[7] << 16);
  lv.x = (u32)l[0] | ((u32)l[1] << 16); lv.y = (u32)l[2] | ((u32)l[3] << 16);
  lv.z = (u32)l[4] | ((u32)l[5] << 16); lv.w = (u32)l[6] | ((u32)l[7] << 16);
  *(uint4*)(A + (size_t)row * BKW + d0) = hv;
  *(uint4*)(A + (size_t)row * BKW + 256 + d0) = lv;
}

// ---------------- prep: split codebook into [hi|lo] bf16, stride 512 -------
__global__ __launch_bounds__(256) void vq_split_cb(const float* __restrict__ cb,
                                                   u16* __restrict__ B) {
  int g = blockIdx.x * 256 + threadIdx.x;   // 8192*32
  int row = g >> 5;
  int d0 = (g & 31) * 8;
  float4 v0 = *(const float4*)(cb + (size_t)row * DIM + d0);
  float4 v1 = *(const float4*)(cb + (size_t)row * DIM + d0 + 4);
  float vv[8] = {v0.x, v0.y, v0.z, v0.w, v1.x, v1.y, v1.z, v1.w};
  u16 h[8], l[8];
#pragma unroll
  for (int i = 0; i < 8; ++i) split2(vv[i], h[i], l[i]);
  uint4 hv, lv;
  hv.x = (u32)h[0] | ((u32)h[1] << 16); hv.y = (u32)h[2] | ((u32)h[3] << 16);
  hv.z = (u32)h[4] | ((u32)h[5] << 16); hv.w = (u32)h[6] | ((u32)h[7] << 16);
  lv.x = (u32)l[0] | ((u32)l[1] << 16); lv.y = (u32)l[2] | ((u32)l[3] << 16);
  lv.z = (u32)l[4] | ((u32)l[5] << 16); lv.w = (u32)l[6] | ((u32)l[7] << 16);
  *(uint4*)(B + (size_t)row * BKW + d0) = hv;
  *(uint4*)(B + (size_t)row * BKW + 256 + d0) = lv;
}

// ---------------- codebook squared norms (f32) ----------------
__global__ __launch_bounds__(256) void vq_c2(const float* __restrict__ cb,
                                             float* __restrict__ c2) {
  int g = blockIdx.x * 256 + threadIdx.x;
  int code = g >> 6;
  int lane = g & 63;
  float4 v = *(const float4*)(cb + (size_t)code * DIM + lane * 4);
  float s = v.x * v.x + v.y * v.y + v.z * v.z + v.w * v.w;
#pragma unroll
  for (int m = 32; m >= 1; m >>= 1) s += __shfl_xor(s, m, 64);
  if (lane == 0) c2[code] = s;
}

// ---------------- main: bf16 MFMA distance GEMM + fused top-2 argmin -------
// Block: 256 thr = 4 waves, partitioned over ROWS only: wave w owns rows
// [w*32, w*32+32) x ALL 128 codes of the tile (no cross-wave row sharing ->
// no partials write race). acc[8][2]: m = code frag (8x16=128), n = row frag.
// Logical K=768 in 24 steps of 32.
__global__ __launch_bounds__(256, 2)
void vq_mfma(const u16* __restrict__ XB, const u16* __restrict__ CB,
             const float* __restrict__ c2g, float* __restrict__ partials) {
  __shared__ __align__(16) u16 As[128 * 32];  // codes x k
  __shared__ __align__(16) u16 Bs[128 * 32];  // x rows x k
  const int t = threadIdx.x;
  const int wid = t >> 6;
  const int lane = t & 63;
  const int lhi = lane >> 4, llo = lane & 15;
  const int rt = blockIdx.x & 255;
  const int s = blockIdx.x >> 8;
  const int row0 = rt * 128;
  const int codeS0 = s * (KCODES / NSPLIT);

  char* AsB = (char*)As;
  char* BsB = (char*)Bs;

  float v1[2], v2[2];
  int i1[2], i2[2];
#pragma unroll
  for (int n = 0; n < 2; ++n) { v1[n] = INFINITY; v2[n] = INFINITY; i1[n] = 0; i2[n] = 0; }

  const int r0 = t >> 2, c80 = (t & 3) << 3;        // staging decomposition
  const int r1 = (256 + t) >> 2, c81 = ((256 + t) & 3) << 3;

#pragma unroll 1
  for (int ct = 0; ct < 16; ++ct) {
    const int code0 = codeS0 + ct * 128;
    f32x4 acc[8][2];
#pragma unroll
    for (int m = 0; m < 8; ++m)
#pragma unroll
      for (int n = 0; n < 2; ++n) acc[m][n] = (f32x4){0.f, 0.f, 0.f, 0.f};

#pragma unroll 1
    for (int ks = 0; ks < 24; ++ks) {
      const int k0 = ks * 32;
      const int aksrc = (k0 < 256) ? k0 : (k0 - 256);   // x:  hi, hi, lo
      const int bksrc = (k0 < 512) ? k0 : (k0 - 512);   // cb: hi, lo, hi
      {
        const u16* sa0 = CB + (size_t)(code0 + r0) * BKW + bksrc + c80;
        const u16* sa1 = CB + (size_t)(code0 + r1) * BKW + bksrc + c81;
        __builtin_amdgcn_global_load_lds((gvoid_t*)sa0, (lvoid_t*)(AsB + (wid << 10)), 16, 0, 0);
        __builtin_amdgcn_global_load_lds((gvoid_t*)sa1, (lvoid_t*)(AsB + 4096 + (wid << 10)), 16, 0, 0);
        const u16* sb0 = XB + (size_t)(row0 + r0) * BKW + aksrc + c80;
        const u16* sb1 = XB + (size_t)(row0 + r1) * BKW + aksrc + c81;
        __builtin_amdgcn_global_load_lds((gvoid_t*)sb0, (lvoid_t*)(BsB + (wid << 10)), 16, 0, 0);
        __builtin_amdgcn_global_load_lds((gvoid_t*)sb1, (lvoid_t*)(BsB + 4096 + (wid << 10)), 16, 0, 0);
      }
      __syncthreads();
      bf16x8 a[8], b[2];
#pragma unroll
      for (int m = 0; m < 8; ++m)
        a[m] = *(const bf16x8*)(AsB + (((m * 16 + llo) << 6) + (lhi << 4)));
#pragma unroll
      for (int n = 0; n < 2; ++n)
        b[n] = *(const bf16x8*)(BsB + (((wid * 32 + n * 16 + llo) << 6) + (lhi << 4)));
#pragma unroll
      for (int m = 0; m < 8; ++m)
#pragma unroll
        for (int n = 0; n < 2; ++n)
          acc[m][n] = __builtin_amdgcn_mfma_f32_16x16x32_bf16(a[m], b[n], acc[m][n], 0, 0, 0);
      __syncthreads();
    }
    // dist = c2 - 2*dot; running top-2 per row-entry n (codes ascending)
#pragma unroll
    for (int m = 0; m < 8; ++m) {
      int cbase = code0 + m * 16 + lhi * 4;
      float4 cv = *(const float4*)(c2g + cbase);
      float cvv[4] = {cv.x, cv.y, cv.z, cv.w};
#pragma unroll
      for (int n = 0; n < 2; ++n) {
#pragma unroll
        for (int r = 0; r < 4; ++r) {
          float d = fmaf(-2.0f, acc[m][n][r], cvv[r]);
          int code = cbase + r;
          bool c1 = d < v1[n];
          bool c2b = d < v2[n];
          v2[n] = c1 ? v1[n] : (c2b ? d : v2[n]);
          i2[n] = c1 ? i1[n] : (c2b ? code : i2[n]);
          v1[n] = c1 ? d : v1[n];
          i1[n] = c1 ? code : i1[n];
        }
      }
    }
  }
  // merge across the 4 lhi groups sharing each row (full 128-code coverage
  // lives within this wave, so this completes the tile reduction)
#pragma unroll
  for (int n = 0; n < 2; ++n) {
    float a1 = v1[n], a2 = v2[n];
    int b1 = i1[n], b2 = i2[n];
#pragma unroll
    for (int mask = 16; mask <= 32; mask <<= 1) {
      float w1 = __shfl_xor(a1, mask, 64);
      int j1 = __shfl_xor(b1, mask, 64);
      float w2 = __shfl_xor(a2, mask, 64);
      int j2 = __shfl_xor(b2, mask, 64);
      merge2(a1, b1, a2, b2, w1, j1, w2, j2);
    }
    if (lhi == 0) {
      int row = row0 + wid * 32 + n * 16 + llo;   // unique writer per row
      float4 out = {a1, __int_as_float(b1), a2, __int_as_float(b2)};
      *(float4*)(partials + ((size_t)row * NSPLIT + s) * 4) = out;
    }
  }
}

// ------ merge splits + re-rank top-2 with np-style f32 (c2 - 2*dot) --------
__global__ __launch_bounds__(256)
void vq_pick(const float* __restrict__ x, const float* __restrict__ cb,
             const float* __restrict__ c2g, const float* __restrict__ partials,
             int* __restrict__ ind) {
  int wid = threadIdx.x >> 6, lane = threadIdx.x & 63;
  int row = blockIdx.x * 4 + wid;
  float v1 = INFINITY, v2 = INFINITY;
  int i1 = 0, i2 = 0;
#pragma unroll
  for (int s = 0; s < NSPLIT; ++s) {
    float4 p = *(const float4*)(partials + ((size_t)row * NSPLIT + s) * 4);
    merge2(v1, i1, v2, i2, p.x, __float_as_int(p.y), p.z, __float_as_int(p.w));
  }
  // np-matching re-rank: d = c2[k] - 2 * dot(x, c_k), f32
  float4 xv = *(const float4*)(x + (size_t)row * DIM + lane * 4);
  float4 ca = *(const float4*)(cb + (size_t)i1 * DIM + lane * 4);
  float4 cbv = *(const float4*)(cb + (size_t)i2 * DIM + lane * 4);
  float da = xv.x * ca.x + xv.y * ca.y + xv.z * ca.z + xv.w * ca.w;
  float db = xv.x * cbv.x + xv.y * cbv.y + xv.z * cbv.z + xv.w * cbv.w;
#pragma unroll
  for (int m = 32; m >= 1; m >>= 1) {
    da += __shfl_xor(da, m, 64);
    db += __shfl_xor(db, m, 64);
  }
  float d1 = fmaf(-2.0f, da, c2g[i1]);
  float d2 = fmaf(-2.0f, db, c2g[i2]);
  bool swap = (d2 < d1) || (d2 == d1 && i2 < i1);
  int k = swap ? i2 : i1;
  if (lane == 0) ind[row] = k;
}

// ---------------- epilogue: gather + loss + scatter stats ------------------
__global__ __launch_bounds__(256)
void vq_epi(const float* __restrict__ x, const float* __restrict__ cb,
            const int* __restrict__ ind, float* __restrict__ out_q,
            float* __restrict__ out_ind, float* __restrict__ out_loss,
            float* __restrict__ out_cs, float* __restrict__ out_es) {
  int wid = threadIdx.x >> 6;
  int lane = threadIdx.x & 63;
  int row = blockIdx.x * 4 + wid;
  int k = ind[row];
  const float4 q = *(const float4*)(cb + (size_t)k * DIM + lane * 4);
  const float4 xv = *(const float4*)(x + (size_t)row * DIM + lane * 4);
  *(float4*)(out_q + (size_t)row * DIM + lane * 4) = q;
  float dx = q.x - xv.x, dy = q.y - xv.y, dz = q.z - xv.z, dw = q.w - xv.w;
  float sv = dx * dx + dy * dy + dz * dz + dw * dw;
#pragma unroll
  for (int m = 32; m >= 1; m >>= 1) sv += __shfl_xor(sv, m, 64);
  if (lane == 0) {
    atomicAdd(out_loss, sv * (1.0f / 8388608.0f));
    atomicAdd(out_cs + k, 1.0f);
    out_ind[row] = (float)k;
  }
  atomicAdd(out_es + (size_t)k * DIM + lane * 4 + 0, xv.x);
  atomicAdd(out_es + (size_t)k * DIM + lane * 4 + 1, xv.y);
  atomicAdd(out_es + (size_t)k * DIM + lane * 4 + 2, xv.z);
  atomicAdd(out_es + (size_t)k * DIM + lane * 4 + 3, xv.w);
}

extern "C" void kernel_launch(void* const* d_in, const int* in_sizes, int n_in,
                              void* d_out, int out_size, void* d_ws,
                              size_t ws_size, hipStream_t stream) {
  const float* x = (const float*)d_in[0];
  const float* cb = (const float*)d_in[1];
  float* out = (float*)d_out;
  float* out_q = out;
  float* out_ind = out + OUT_IND;
  float* out_loss = out + OUT_LOSS;
  float* out_cs = out + OUT_CS;
  float* out_es = out + OUT_ES;

  // Scratch-in-output: Abuf == out_q region (exact 32 MB fit; rewritten by
  // vq_epi last). Bbuf == out+OUT_IND (16B-aligned, 8 MB <= 8.55 MB tail;
  // tail memset-zeroed after the GEMM, before the atomics).
  u16* Abuf = (u16*)out;
  u16* Bbuf = (u16*)(out + OUT_IND);

  char* w = (char*)d_ws;                         // total ws use: ~2.21 MB
  float* c2 = (float*)w;                         // 32 KB
  int* ind = (int*)(w + (32 << 10));             // 128 KB
  float* partials = (float*)(w + (160 << 10));   // 2 MB

  vq_split_x<<<4096, 256, 0, stream>>>(x, Abuf);
  vq_split_cb<<<1024, 256, 0, stream>>>(cb, Bbuf);
  vq_c2<<<2048, 256, 0, stream>>>(cb, c2);
  vq_mfma<<<256 * NSPLIT, 256, 0, stream>>>(Abuf, Bbuf, c2, partials);
  // zero out_ind..out_es tail (kills Bbuf scratch; preps atomics)
  hipMemsetAsync(out + OUT_IND, 0, (size_t)(OUT_TOTAL - OUT_IND) * sizeof(float),
                 stream);
  vq_pick<<<BN_TOTAL / 4, 256, 0, stream>>>(x, cb, c2, partials, ind);
  vq_epi<<<BN_TOTAL / 4, 256, 0, stream>>>(x, cb, ind, out_q, out_ind, out_loss,
                                           out_cs, out_es);
}

// Round 5
// 656.642 us; speedup vs baseline: 4.2244x; 1.4439x over previous
//
#include <hip/hip_runtime.h>
#include <hip/hip_bf16.h>
#include <math.h>

#define DIM 256
#define KCODES 8192
#define BN_TOTAL 32768
#define NSPLIT 4

// d_out flat f32 layout (reference return order)
#define OUT_IND 8388608
#define OUT_LOSS 8421376
#define OUT_CS 8421377
#define OUT_ES 8429569
#define OUT_TOTAL 10526721
#define P_OFF 4194304   // partials float offset inside out_q region (byte 16MB)

typedef unsigned short u16;
typedef unsigned int u32;
typedef __attribute__((ext_vector_type(8))) short bf16x8;
typedef __attribute__((ext_vector_type(4))) float f32x4;
typedef __attribute__((address_space(1))) const void gvoid_t;
typedef __attribute__((address_space(3))) void lvoid_t;

// merge two lex-sorted top2 pairs
__device__ __forceinline__ void merge2(float& a1, int& b1, float& a2, int& b2,
                                       float w1, int j1, float w2, int j2) {
  bool less = (w1 < a1) || (w1 == a1 && j1 < b1);
  float t1v = less ? w1 : a1; int t1i = less ? j1 : b1;
  float ov  = less ? a1 : w1; int oi  = less ? b1 : j1;
  float sv  = less ? w2 : a2; int si  = less ? j2 : b2;
  bool less2 = (sv < ov) || (sv == ov && si < oi);
  a1 = t1v; b1 = t1i;
  a2 = less2 ? sv : ov; b2 = less2 ? si : oi;
}

// ---------------- prep: x -> bf16 hi, stride 256 ----------------
__global__ __launch_bounds__(256) void vq_split_x(const float* __restrict__ x,
                                                  u16* __restrict__ A) {
  int g = blockIdx.x * 256 + threadIdx.x;   // 32768*32 threads
  int row = g >> 5;
  int d0 = (g & 31) * 8;
  float4 v0 = *(const float4*)(x + (size_t)row * DIM + d0);
  float4 v1 = *(const float4*)(x + (size_t)row * DIM + d0 + 4);
  float vv[8] = {v0.x, v0.y, v0.z, v0.w, v1.x, v1.y, v1.z, v1.w};
  u16 h[8];
#pragma unroll
  for (int i = 0; i < 8; ++i) {
    __hip_bfloat16 b = __float2bfloat16(vv[i]);
    h[i] = *reinterpret_cast<u16*>(&b);
  }
  uint4 hv;
  hv.x = (u32)h[0] | ((u32)h[1] << 16); hv.y = (u32)h[2] | ((u32)h[3] << 16);
  hv.z = (u32)h[4] | ((u32)h[5] << 16); hv.w = (u32)h[6] | ((u32)h[7] << 16);
  *(uint4*)(A + (size_t)row * DIM + d0) = hv;
}

// ---------------- prep: cb -> bf16 hi + exact f32 norms (fused) ------------
__global__ __launch_bounds__(256) void vq_split_cb_c2(const float* __restrict__ cb,
                                                      u16* __restrict__ B,
                                                      float* __restrict__ c2) {
  int g = blockIdx.x * 256 + threadIdx.x;   // 8192*32 threads
  int code = g >> 5;
  int l5 = g & 31;
  int d0 = l5 * 8;
  float4 v0 = *(const float4*)(cb + (size_t)code * DIM + d0);
  float4 v1 = *(const float4*)(cb + (size_t)code * DIM + d0 + 4);
  float vv[8] = {v0.x, v0.y, v0.z, v0.w, v1.x, v1.y, v1.z, v1.w};
  u16 h[8];
  float s = 0.0f;
#pragma unroll
  for (int i = 0; i < 8; ++i) {
    __hip_bfloat16 b = __float2bfloat16(vv[i]);
    h[i] = *reinterpret_cast<u16*>(&b);
    s += vv[i] * vv[i];
  }
  uint4 hv;
  hv.x = (u32)h[0] | ((u32)h[1] << 16); hv.y = (u32)h[2] | ((u32)h[3] << 16);
  hv.z = (u32)h[4] | ((u32)h[5] << 16); hv.w = (u32)h[6] | ((u32)h[7] << 16);
  *(uint4*)(B + (size_t)code * DIM + d0) = hv;
#pragma unroll
  for (int m = 1; m <= 16; m <<= 1) s += __shfl_xor(s, m, 64);  // 32-lane group
  if (l5 == 0) c2[code] = s;
}

// ---------------- main: K=256 bf16 MFMA + fused per-slice top-2 argmin -----
// Block: 256 thr = 4 waves over ROWS (wave w: rows w*32..+32, all 128 codes).
// B (x rows) preloaded to registers; As (codes) double-buffered 2x8KB via
// global_load_lds, staged one 32-k step ahead.
__global__ __launch_bounds__(256, 2)
void vq_mfma(const u16* __restrict__ XB, const u16* __restrict__ CBb,
             const float* __restrict__ c2g, float* __restrict__ partials) {
  __shared__ __align__(16) u16 As[2][4096];
  const int t = threadIdx.x;
  const int wid = t >> 6;
  const int lane = t & 63;
  const int lhi = lane >> 4, llo = lane & 15;
  const int rt = blockIdx.x & 255;
  const int s = blockIdx.x >> 8;
  const int row0 = rt * 128;
  const int code0base = s * (KCODES / NSPLIT);

  // preload B fragments: b[n][ks] (row row0+wid*32+n*16+llo, k = ks*32+lhi*8)
  bf16x8 b[2][8];
#pragma unroll
  for (int n = 0; n < 2; ++n) {
    const u16* bp = XB + (size_t)(row0 + wid * 32 + n * 16 + llo) * DIM + lhi * 8;
#pragma unroll
    for (int ks = 0; ks < 8; ++ks)
      b[n][ks] = *(const bf16x8*)(bp + ks * 32);
  }

  char* AsB = (char*)As;
  const int r0 = t >> 2, c80 = (t & 3) << 3;
  const int r1 = 64 + r0;

  float v1[2], v2[2];
  int i1[2], i2[2];
#pragma unroll
  for (int n = 0; n < 2; ++n) { v1[n] = INFINITY; v2[n] = INFINITY; i1[n] = 0; i2[n] = 0; }

  // prologue: stage (ct=0, ks=0) into buf 0
  {
    const u16* sa0 = CBb + (size_t)(code0base + r0) * DIM + c80;
    const u16* sa1 = CBb + (size_t)(code0base + r1) * DIM + c80;
    __builtin_amdgcn_global_load_lds((gvoid_t*)sa0, (lvoid_t*)(AsB + (wid << 10)), 16, 0, 0);
    __builtin_amdgcn_global_load_lds((gvoid_t*)sa1, (lvoid_t*)(AsB + 4096 + (wid << 10)), 16, 0, 0);
  }
  __syncthreads();

#pragma unroll 1
  for (int ct = 0; ct < 16; ++ct) {
    const int code0 = code0base + ct * 128;
    f32x4 acc[8][2];
#pragma unroll
    for (int m = 0; m < 8; ++m)
#pragma unroll
      for (int n = 0; n < 2; ++n) acc[m][n] = (f32x4){0.f, 0.f, 0.f, 0.f};

#pragma unroll
    for (int ks = 0; ks < 8; ++ks) {
      const int cur = ks & 1;
      // stage next 32-k step into the other buffer (overlaps with MFMA below)
      if (!(ct == 15 && ks == 7)) {
        const int nct = (ks == 7) ? ct + 1 : ct;
        const int nks = (ks == 7) ? 0 : ks + 1;
        const u16* sa0 = CBb + (size_t)(code0base + nct * 128 + r0) * DIM + nks * 32 + c80;
        const u16* sa1 = CBb + (size_t)(code0base + nct * 128 + r1) * DIM + nks * 32 + c80;
        char* dst = AsB + ((cur ^ 1) << 13);
        __builtin_amdgcn_global_load_lds((gvoid_t*)sa0, (lvoid_t*)(dst + (wid << 10)), 16, 0, 0);
        __builtin_amdgcn_global_load_lds((gvoid_t*)sa1, (lvoid_t*)(dst + 4096 + (wid << 10)), 16, 0, 0);
      }
      const char* src = AsB + (cur << 13);
      bf16x8 a[8];
#pragma unroll
      for (int m = 0; m < 8; ++m)
        a[m] = *(const bf16x8*)(src + (((m * 16 + llo) << 6) + (lhi << 4)));
#pragma unroll
      for (int m = 0; m < 8; ++m) {
        acc[m][0] = __builtin_amdgcn_mfma_f32_16x16x32_bf16(a[m], b[0][ks], acc[m][0], 0, 0, 0);
        acc[m][1] = __builtin_amdgcn_mfma_f32_16x16x32_bf16(a[m], b[1][ks], acc[m][1], 0, 0, 0);
      }
      // argmin epilogue overlaps the ks=7 staged-load drain
      if (ks == 7) {
#pragma unroll
        for (int m = 0; m < 8; ++m) {
          int cbase = code0 + m * 16 + lhi * 4;
          float4 cv = *(const float4*)(c2g + cbase);
          float cvv[4] = {cv.x, cv.y, cv.z, cv.w};
#pragma unroll
          for (int n = 0; n < 2; ++n) {
#pragma unroll
            for (int r = 0; r < 4; ++r) {
              float d = fmaf(-2.0f, acc[m][n][r], cvv[r]);
              int code = cbase + r;
              bool c1 = d < v1[n];
              bool c2b = d < v2[n];
              v2[n] = c1 ? v1[n] : (c2b ? d : v2[n]);
              i2[n] = c1 ? i1[n] : (c2b ? code : i2[n]);
              v1[n] = c1 ? d : v1[n];
              i1[n] = c1 ? code : i1[n];
            }
          }
        }
      }
      __syncthreads();
    }
  }
  // merge lhi pairs (0<->1, 2<->3): top-2 per 1024-code slice; 2 slots/row/split
#pragma unroll
  for (int n = 0; n < 2; ++n) {
    float a1 = v1[n], a2 = v2[n];
    int b1 = i1[n], b2 = i2[n];
    float w1 = __shfl_xor(a1, 16, 64);
    int j1 = __shfl_xor(b1, 16, 64);
    float w2 = __shfl_xor(a2, 16, 64);
    int j2 = __shfl_xor(b2, 16, 64);
    merge2(a1, b1, a2, b2, w1, j1, w2, j2);
    if ((lhi & 1) == 0) {
      int row = row0 + wid * 32 + n * 16 + llo;
      int gslot = lhi >> 1;
      float4 o = {a1, __int_as_float(b1), a2, __int_as_float(b2)};
      *(float4*)(partials + ((size_t)(row * NSPLIT + s) * 2 + gslot) * 4) = o;
    }
  }
}

// ---- merge 16 candidates -> approx top-4 -> exact f32 rescore -> index ----
__global__ __launch_bounds__(256)
void vq_pick(const float* __restrict__ x, const float* __restrict__ cb,
             const float* __restrict__ c2g, const float* __restrict__ partials,
             int* __restrict__ ind) {
  int wid = threadIdx.x >> 6, lane = threadIdx.x & 63;
  int row = blockIdx.x * 4 + wid;
  float cv = INFINITY, cv2 = INFINITY;
  int ci = 0x7FFFFFFF, ci2 = 0x7FFFFFFF;
  if (lane < 8) {
    float4 p = *(const float4*)(partials + ((size_t)row * 8 + lane) * 4);
    cv = p.x; ci = __float_as_int(p.y); cv2 = p.z; ci2 = __float_as_int(p.w);
  }
  int cand[4];
#pragma unroll
  for (int rsel = 0; rsel < 4; ++rsel) {
    float bv = cv; int bi = ci;
#pragma unroll
    for (int mask = 1; mask < 64; mask <<= 1) {
      float wv = __shfl_xor(bv, mask, 64);
      int wi = __shfl_xor(bi, mask, 64);
      if (wv < bv || (wv == bv && wi < bi)) { bv = wv; bi = wi; }
    }
    cand[rsel] = bi;
    if (ci == bi) { cv = cv2; ci = ci2; cv2 = INFINITY; ci2 = 0x7FFFFFFF; }
  }
  const float4 xv = *(const float4*)(x + (size_t)row * DIM + lane * 4);
  float4 q0 = *(const float4*)(cb + (size_t)cand[0] * DIM + lane * 4);
  float4 q1 = *(const float4*)(cb + (size_t)cand[1] * DIM + lane * 4);
  float4 q2 = *(const float4*)(cb + (size_t)cand[2] * DIM + lane * 4);
  float4 q3 = *(const float4*)(cb + (size_t)cand[3] * DIM + lane * 4);
  float d0 = xv.x * q0.x + xv.y * q0.y + xv.z * q0.z + xv.w * q0.w;
  float d1 = xv.x * q1.x + xv.y * q1.y + xv.z * q1.z + xv.w * q1.w;
  float d2 = xv.x * q2.x + xv.y * q2.y + xv.z * q2.z + xv.w * q2.w;
  float d3 = xv.x * q3.x + xv.y * q3.y + xv.z * q3.z + xv.w * q3.w;
#pragma unroll
  for (int mask = 1; mask < 64; mask <<= 1) {
    d0 += __shfl_xor(d0, mask, 64);
    d1 += __shfl_xor(d1, mask, 64);
    d2 += __shfl_xor(d2, mask, 64);
    d3 += __shfl_xor(d3, mask, 64);
  }
  float e0 = fmaf(-2.0f, d0, c2g[cand[0]]);
  float e1 = fmaf(-2.0f, d1, c2g[cand[1]]);
  float e2 = fmaf(-2.0f, d2, c2g[cand[2]]);
  float e3 = fmaf(-2.0f, d3, c2g[cand[3]]);
  float best = e0; int bk = cand[0];
  if (e1 < best || (e1 == best && cand[1] < bk)) { best = e1; bk = cand[1]; }
  if (e2 < best || (e2 == best && cand[2] < bk)) { best = e2; bk = cand[2]; }
  if (e3 < best || (e3 == best && cand[3] < bk)) { best = e3; bk = cand[3]; }
  if (lane == 0) ind[row] = bk;
}

// ---------------- epilogue: gather + loss + scatter stats ------------------
__global__ __launch_bounds__(256)
void vq_epi(const float* __restrict__ x, const float* __restrict__ cb,
            const int* __restrict__ ind, float* __restrict__ out_q,
            float* __restrict__ out_ind, float* __restrict__ out_loss,
            float* __restrict__ out_cs, float* __restrict__ out_es) {
  int wid = threadIdx.x >> 6;
  int lane = threadIdx.x & 63;
  int row = blockIdx.x * 4 + wid;
  int k = ind[row];
  const float4 q = *(const float4*)(cb + (size_t)k * DIM + lane * 4);
  const float4 xv = *(const float4*)(x + (size_t)row * DIM + lane * 4);
  *(float4*)(out_q + (size_t)row * DIM + lane * 4) = q;
  float dx = q.x - xv.x, dy = q.y - xv.y, dz = q.z - xv.z, dw = q.w - xv.w;
  float sv = dx * dx + dy * dy + dz * dz + dw * dw;
#pragma unroll
  for (int m = 32; m >= 1; m >>= 1) sv += __shfl_xor(sv, m, 64);
  if (lane == 0) {
    atomicAdd(out_loss, sv * (1.0f / 8388608.0f));
    atomicAdd(out_cs + k, 1.0f);
    out_ind[row] = (float)k;
  }
  atomicAdd(out_es + (size_t)k * DIM + lane * 4 + 0, xv.x);
  atomicAdd(out_es + (size_t)k * DIM + lane * 4 + 1, xv.y);
  atomicAdd(out_es + (size_t)k * DIM + lane * 4 + 2, xv.z);
  atomicAdd(out_es + (size_t)k * DIM + lane * 4 + 3, xv.w);
}

extern "C" void kernel_launch(void* const* d_in, const int* in_sizes, int n_in,
                              void* d_out, int out_size, void* d_ws,
                              size_t ws_size, hipStream_t stream) {
  const float* x = (const float*)d_in[0];
  const float* cb = (const float*)d_in[1];
  float* out = (float*)d_out;
  float* out_q = out;
  float* out_ind = out + OUT_IND;
  float* out_loss = out + OUT_LOSS;
  float* out_cs = out + OUT_CS;
  float* out_es = out + OUT_ES;

  // Scratch-in-output:
  //  Abuf (x hi bf16, 16 MB)     = out[0 .. 4M floats)       -- dead after mfma
  //  partials (4 MB)             = out[4M .. 5.25M floats)   -- dead after pick
  //  CBb (cb hi bf16, 4 MB)      = out[OUT_IND ..)           -- dead after mfma
  // vq_epi rewrites all of out_q last; memset clears the tail before atomics.
  u16* Abuf = (u16*)out;
  float* partials = out + P_OFF;
  u16* CBb = (u16*)(out + OUT_IND);

  char* w = (char*)d_ws;              // ws use: 160 KB (proven available)
  float* c2 = (float*)w;              // 32 KB
  int* ind = (int*)(w + (32 << 10));  // 128 KB

  vq_split_x<<<4096, 256, 0, stream>>>(x, Abuf);
  vq_split_cb_c2<<<1024, 256, 0, stream>>>(cb, CBb, c2);
  vq_mfma<<<256 * NSPLIT, 256, 0, stream>>>(Abuf, CBb, c2, partials);
  vq_pick<<<BN_TOTAL / 4, 256, 0, stream>>>(x, cb, c2, partials, ind);
  hipMemsetAsync(out + OUT_IND, 0, (size_t)(OUT_TOTAL - OUT_IND) * sizeof(float),
                 stream);
  vq_epi<<<BN_TOTAL / 4, 256, 0, stream>>>(x, cb, ind, out_q, out_ind, out_loss,
                                           out_cs, out_es);
}

// Round 6
// 393.669 us; speedup vs baseline: 7.0464x; 1.6680x over previous
//
#include <hip/hip_runtime.h>
#include <hip/hip_bf16.h>
#include <math.h>

#define DIM 256
#define KCODES 8192
#define BN_TOTAL 32768
#define NSPLIT 4

// d_out flat f32 layout (reference return order)
#define OUT_IND 8388608
#define OUT_LOSS 8421376
#define OUT_CS 8421377
#define OUT_ES 8429569
#define OUT_TOTAL 10526721

// scratch inside dead half of out_q region (all dead before vq_out runs)
#define P_OFF 4194304        // partials: 32768 rows * 8 slots * 4 f32 = 1M f32
#define CNT_OFF 5242880      // cnt:   8192 i32
#define OFFS_OFF 5251072     // offs:  8192 i32
#define WOFFS_OFF 5259264    // woffs: 8192 i32
#define LP_OFF 5267456       // loss_part: 8192 f32
#define RL_OFF 5275648       // rowlist: 32768 i32 (ends 5308416 < 8388608)

typedef unsigned short u16;
typedef unsigned int u32;
typedef __attribute__((ext_vector_type(8))) short bf16x8;
typedef __attribute__((ext_vector_type(4))) float f32x4;
typedef __attribute__((address_space(1))) const void gvoid_t;
typedef __attribute__((address_space(3))) void lvoid_t;

// merge two lex-sorted top2 pairs
__device__ __forceinline__ void merge2(float& a1, int& b1, float& a2, int& b2,
                                       float w1, int j1, float w2, int j2) {
  bool less = (w1 < a1) || (w1 == a1 && j1 < b1);
  float t1v = less ? w1 : a1; int t1i = less ? j1 : b1;
  float ov  = less ? a1 : w1; int oi  = less ? b1 : j1;
  float sv  = less ? w2 : a2; int si  = less ? j2 : b2;
  bool less2 = (sv < ov) || (sv == ov && si < oi);
  a1 = t1v; b1 = t1i;
  a2 = less2 ? sv : ov; b2 = less2 ? si : oi;
}

// ---------------- prep: x -> bf16 hi, stride 256 ----------------
__global__ __launch_bounds__(256) void vq_split_x(const float* __restrict__ x,
                                                  u16* __restrict__ A) {
  int g = blockIdx.x * 256 + threadIdx.x;
  int row = g >> 5;
  int d0 = (g & 31) * 8;
  float4 v0 = *(const float4*)(x + (size_t)row * DIM + d0);
  float4 v1 = *(const float4*)(x + (size_t)row * DIM + d0 + 4);
  float vv[8] = {v0.x, v0.y, v0.z, v0.w, v1.x, v1.y, v1.z, v1.w};
  u16 h[8];
#pragma unroll
  for (int i = 0; i < 8; ++i) {
    __hip_bfloat16 b = __float2bfloat16(vv[i]);
    h[i] = *reinterpret_cast<u16*>(&b);
  }
  uint4 hv;
  hv.x = (u32)h[0] | ((u32)h[1] << 16); hv.y = (u32)h[2] | ((u32)h[3] << 16);
  hv.z = (u32)h[4] | ((u32)h[5] << 16); hv.w = (u32)h[6] | ((u32)h[7] << 16);
  *(uint4*)(A + (size_t)row * DIM + d0) = hv;
}

// ---------------- prep: cb -> bf16 hi + exact f32 norms (fused) ------------
__global__ __launch_bounds__(256) void vq_split_cb_c2(const float* __restrict__ cb,
                                                      u16* __restrict__ B,
                                                      float* __restrict__ c2) {
  int g = blockIdx.x * 256 + threadIdx.x;
  int code = g >> 5;
  int l5 = g & 31;
  int d0 = l5 * 8;
  float4 v0 = *(const float4*)(cb + (size_t)code * DIM + d0);
  float4 v1 = *(const float4*)(cb + (size_t)code * DIM + d0 + 4);
  float vv[8] = {v0.x, v0.y, v0.z, v0.w, v1.x, v1.y, v1.z, v1.w};
  u16 h[8];
  float s = 0.0f;
#pragma unroll
  for (int i = 0; i < 8; ++i) {
    __hip_bfloat16 b = __float2bfloat16(vv[i]);
    h[i] = *reinterpret_cast<u16*>(&b);
    s += vv[i] * vv[i];
  }
  uint4 hv;
  hv.x = (u32)h[0] | ((u32)h[1] << 16); hv.y = (u32)h[2] | ((u32)h[3] << 16);
  hv.z = (u32)h[4] | ((u32)h[5] << 16); hv.w = (u32)h[6] | ((u32)h[7] << 16);
  *(uint4*)(B + (size_t)code * DIM + d0) = hv;
#pragma unroll
  for (int m = 1; m <= 16; m <<= 1) s += __shfl_xor(s, m, 64);
  if (l5 == 0) c2[code] = s;
}

// ---------------- main: K=256 bf16 MFMA + fused per-slice top-2 argmin -----
// (unchanged from round 5 — passing index path)
__global__ __launch_bounds__(256, 2)
void vq_mfma(const u16* __restrict__ XB, const u16* __restrict__ CBb,
             const float* __restrict__ c2g, float* __restrict__ partials) {
  __shared__ __align__(16) u16 As[2][4096];
  const int t = threadIdx.x;
  const int wid = t >> 6;
  const int lane = t & 63;
  const int lhi = lane >> 4, llo = lane & 15;
  const int rt = blockIdx.x & 255;
  const int s = blockIdx.x >> 8;
  const int row0 = rt * 128;
  const int code0base = s * (KCODES / NSPLIT);

  bf16x8 b[2][8];
#pragma unroll
  for (int n = 0; n < 2; ++n) {
    const u16* bp = XB + (size_t)(row0 + wid * 32 + n * 16 + llo) * DIM + lhi * 8;
#pragma unroll
    for (int ks = 0; ks < 8; ++ks)
      b[n][ks] = *(const bf16x8*)(bp + ks * 32);
  }

  char* AsB = (char*)As;
  const int r0 = t >> 2, c80 = (t & 3) << 3;
  const int r1 = 64 + r0;

  float v1[2], v2[2];
  int i1[2], i2[2];
#pragma unroll
  for (int n = 0; n < 2; ++n) { v1[n] = INFINITY; v2[n] = INFINITY; i1[n] = 0; i2[n] = 0; }

  {
    const u16* sa0 = CBb + (size_t)(code0base + r0) * DIM + c80;
    const u16* sa1 = CBb + (size_t)(code0base + r1) * DIM + c80;
    __builtin_amdgcn_global_load_lds((gvoid_t*)sa0, (lvoid_t*)(AsB + (wid << 10)), 16, 0, 0);
    __builtin_amdgcn_global_load_lds((gvoid_t*)sa1, (lvoid_t*)(AsB + 4096 + (wid << 10)), 16, 0, 0);
  }
  __syncthreads();

#pragma unroll 1
  for (int ct = 0; ct < 16; ++ct) {
    const int code0 = code0base + ct * 128;
    f32x4 acc[8][2];
#pragma unroll
    for (int m = 0; m < 8; ++m)
#pragma unroll
      for (int n = 0; n < 2; ++n) acc[m][n] = (f32x4){0.f, 0.f, 0.f, 0.f};

#pragma unroll
    for (int ks = 0; ks < 8; ++ks) {
      const int cur = ks & 1;
      if (!(ct == 15 && ks == 7)) {
        const int nct = (ks == 7) ? ct + 1 : ct;
        const int nks = (ks == 7) ? 0 : ks + 1;
        const u16* sa0 = CBb + (size_t)(code0base + nct * 128 + r0) * DIM + nks * 32 + c80;
        const u16* sa1 = CBb + (size_t)(code0base + nct * 128 + r1) * DIM + nks * 32 + c80;
        char* dst = AsB + ((cur ^ 1) << 13);
        __builtin_amdgcn_global_load_lds((gvoid_t*)sa0, (lvoid_t*)(dst + (wid << 10)), 16, 0, 0);
        __builtin_amdgcn_global_load_lds((gvoid_t*)sa1, (lvoid_t*)(dst + 4096 + (wid << 10)), 16, 0, 0);
      }
      const char* src = AsB + (cur << 13);
      bf16x8 a[8];
#pragma unroll
      for (int m = 0; m < 8; ++m)
        a[m] = *(const bf16x8*)(src + (((m * 16 + llo) << 6) + (lhi << 4)));
#pragma unroll
      for (int m = 0; m < 8; ++m) {
        acc[m][0] = __builtin_amdgcn_mfma_f32_16x16x32_bf16(a[m], b[0][ks], acc[m][0], 0, 0, 0);
        acc[m][1] = __builtin_amdgcn_mfma_f32_16x16x32_bf16(a[m], b[1][ks], acc[m][1], 0, 0, 0);
      }
      if (ks == 7) {
#pragma unroll
        for (int m = 0; m < 8; ++m) {
          int cbase = code0 + m * 16 + lhi * 4;
          float4 cv = *(const float4*)(c2g + cbase);
          float cvv[4] = {cv.x, cv.y, cv.z, cv.w};
#pragma unroll
          for (int n = 0; n < 2; ++n) {
#pragma unroll
            for (int r = 0; r < 4; ++r) {
              float d = fmaf(-2.0f, acc[m][n][r], cvv[r]);
              int code = cbase + r;
              bool c1 = d < v1[n];
              bool c2b = d < v2[n];
              v2[n] = c1 ? v1[n] : (c2b ? d : v2[n]);
              i2[n] = c1 ? i1[n] : (c2b ? code : i2[n]);
              v1[n] = c1 ? d : v1[n];
              i1[n] = c1 ? code : i1[n];
            }
          }
        }
      }
      __syncthreads();
    }
  }
#pragma unroll
  for (int n = 0; n < 2; ++n) {
    float a1 = v1[n], a2 = v2[n];
    int b1 = i1[n], b2 = i2[n];
    float w1 = __shfl_xor(a1, 16, 64);
    int j1 = __shfl_xor(b1, 16, 64);
    float w2 = __shfl_xor(a2, 16, 64);
    int j2 = __shfl_xor(b2, 16, 64);
    merge2(a1, b1, a2, b2, w1, j1, w2, j2);
    if ((lhi & 1) == 0) {
      int row = row0 + wid * 32 + n * 16 + llo;
      int gslot = lhi >> 1;
      float4 o = {a1, __int_as_float(b1), a2, __int_as_float(b2)};
      *(float4*)(partials + ((size_t)(row * NSPLIT + s) * 2 + gslot) * 4) = o;
    }
  }
}

// ---- pick: merge 16 cands -> top-4 -> exact rescore -> ind + hist + loss ----
__global__ __launch_bounds__(256)
void vq_pick(const float* __restrict__ x, const float* __restrict__ cb,
             const float* __restrict__ c2g, const float* __restrict__ partials,
             int* __restrict__ ind, float* __restrict__ out_ind,
             int* __restrict__ cnt, float* __restrict__ loss_part) {
  __shared__ float lsm[4];
  int wid = threadIdx.x >> 6, lane = threadIdx.x & 63;
  int row = blockIdx.x * 4 + wid;
  float cv = INFINITY, cv2 = INFINITY;
  int ci = 0x7FFFFFFF, ci2 = 0x7FFFFFFF;
  if (lane < 8) {
    float4 p = *(const float4*)(partials + ((size_t)row * 8 + lane) * 4);
    cv = p.x; ci = __float_as_int(p.y); cv2 = p.z; ci2 = __float_as_int(p.w);
  }
  int cand[4];
#pragma unroll
  for (int rsel = 0; rsel < 4; ++rsel) {
    float bv = cv; int bi = ci;
#pragma unroll
    for (int mask = 1; mask < 64; mask <<= 1) {
      float wv = __shfl_xor(bv, mask, 64);
      int wi = __shfl_xor(bi, mask, 64);
      if (wv < bv || (wv == bv && wi < bi)) { bv = wv; bi = wi; }
    }
    cand[rsel] = bi;
    if (ci == bi) { cv = cv2; ci = ci2; cv2 = INFINITY; ci2 = 0x7FFFFFFF; }
  }
  const float4 xv = *(const float4*)(x + (size_t)row * DIM + lane * 4);
  float4 q0 = *(const float4*)(cb + (size_t)cand[0] * DIM + lane * 4);
  float4 q1 = *(const float4*)(cb + (size_t)cand[1] * DIM + lane * 4);
  float4 q2 = *(const float4*)(cb + (size_t)cand[2] * DIM + lane * 4);
  float4 q3 = *(const float4*)(cb + (size_t)cand[3] * DIM + lane * 4);
  float d0 = xv.x * q0.x + xv.y * q0.y + xv.z * q0.z + xv.w * q0.w;
  float d1 = xv.x * q1.x + xv.y * q1.y + xv.z * q1.z + xv.w * q1.w;
  float d2 = xv.x * q2.x + xv.y * q2.y + xv.z * q2.z + xv.w * q2.w;
  float d3 = xv.x * q3.x + xv.y * q3.y + xv.z * q3.z + xv.w * q3.w;
  float x2 = xv.x * xv.x + xv.y * xv.y + xv.z * xv.z + xv.w * xv.w;
#pragma unroll
  for (int mask = 1; mask < 64; mask <<= 1) {
    d0 += __shfl_xor(d0, mask, 64);
    d1 += __shfl_xor(d1, mask, 64);
    d2 += __shfl_xor(d2, mask, 64);
    d3 += __shfl_xor(d3, mask, 64);
    x2 += __shfl_xor(x2, mask, 64);
  }
  float e0 = fmaf(-2.0f, d0, c2g[cand[0]]);
  float e1 = fmaf(-2.0f, d1, c2g[cand[1]]);
  float e2 = fmaf(-2.0f, d2, c2g[cand[2]]);
  float e3 = fmaf(-2.0f, d3, c2g[cand[3]]);
  float best = e0; int bk = cand[0];
  if (e1 < best || (e1 == best && cand[1] < bk)) { best = e1; bk = cand[1]; }
  if (e2 < best || (e2 == best && cand[2] < bk)) { best = e2; bk = cand[2]; }
  if (e3 < best || (e3 == best && cand[3] < bk)) { best = e3; bk = cand[3]; }
  if (lane == 0) {
    ind[row] = bk;
    out_ind[row] = (float)bk;
    atomicAdd(cnt + bk, 1);
    lsm[wid] = x2 + best;   // == ||q - x||^2 for this row (exact identity)
  }
  __syncthreads();
  if (threadIdx.x == 0)
    loss_part[blockIdx.x] = lsm[0] + lsm[1] + lsm[2] + lsm[3];
}

// ---- scan: exclusive scan cnt -> offs/woffs; out_cs; reduce loss ----
__global__ __launch_bounds__(1024)
void vq_scan(const int* __restrict__ cnt, int* __restrict__ offs,
             int* __restrict__ woffs, float* __restrict__ out_cs,
             const float* __restrict__ loss_part, float* __restrict__ out_loss) {
  __shared__ int ssum[1024];
  __shared__ float sls[1024];
  int tid = threadIdx.x;
  int c[8], loc[8];
  int s = 0;
#pragma unroll
  for (int j = 0; j < 8; ++j) {
    c[j] = cnt[tid * 8 + j];
    loc[j] = s;
    s += c[j];
  }
  ssum[tid] = s;
  float ls = 0.0f;
#pragma unroll
  for (int j = 0; j < 8; ++j) ls += loss_part[tid * 8 + j];
  sls[tid] = ls;
  __syncthreads();
  for (int off = 1; off < 1024; off <<= 1) {
    int v = (tid >= off) ? ssum[tid - off] : 0;
    __syncthreads();
    ssum[tid] += v;
    __syncthreads();
  }
  int base = (tid > 0) ? ssum[tid - 1] : 0;
#pragma unroll
  for (int j = 0; j < 8; ++j) {
    int o = base + loc[j];
    offs[tid * 8 + j] = o;
    woffs[tid * 8 + j] = o;
    out_cs[tid * 8 + j] = (float)c[j];
  }
  for (int off = 512; off >= 1; off >>= 1) {
    if (tid < off) sls[tid] += sls[tid + off];
    __syncthreads();
  }
  if (tid == 0) *out_loss = sls[0] * (1.0f / 8388608.0f);
}

// ---- scatter: build rowlist grouped by code ----
__global__ __launch_bounds__(256)
void vq_scatter(const int* __restrict__ ind, int* __restrict__ woffs,
                int* __restrict__ rowlist) {
  int row = blockIdx.x * 256 + threadIdx.x;
  int k = ind[row];
  int pos = atomicAdd(woffs + k, 1);
  rowlist[pos] = row;
}

// ---- esum: one wave per code, register-accumulated segment sum ----
__global__ __launch_bounds__(256)
void vq_esum(const float* __restrict__ x, const int* __restrict__ offs,
             const int* __restrict__ cnt, const int* __restrict__ rowlist,
             float* __restrict__ out_es) {
  int wid = threadIdx.x >> 6, lane = threadIdx.x & 63;
  int k = blockIdx.x * 4 + wid;
  int start = offs[k], n = cnt[k];
  float4 acc = {0.f, 0.f, 0.f, 0.f};
  for (int base = 0; base < n; base += 64) {
    int r = (base + lane < n) ? rowlist[start + base + lane] : 0;
    int lim = min(64, n - base);
    for (int j = 0; j < lim; ++j) {
      int row = __shfl(r, j, 64);
      float4 xv = *(const float4*)(x + (size_t)row * DIM + lane * 4);
      acc.x += xv.x; acc.y += xv.y; acc.z += xv.z; acc.w += xv.w;
    }
  }
  *(float4*)(out_es + (size_t)k * DIM + lane * 4) = acc;
}

// ---- out: pure gather + store of quantized vectors (runs LAST) ----
__global__ __launch_bounds__(256)
void vq_out(const float* __restrict__ cb, const int* __restrict__ ind,
            float* __restrict__ out_q) {
  int wid = threadIdx.x >> 6, lane = threadIdx.x & 63;
  int row = blockIdx.x * 4 + wid;
  int k = ind[row];
  float4 q = *(const float4*)(cb + (size_t)k * DIM + lane * 4);
  *(float4*)(out_q + (size_t)row * DIM + lane * 4) = q;
}

extern "C" void kernel_launch(void* const* d_in, const int* in_sizes, int n_in,
                              void* d_out, int out_size, void* d_ws,
                              size_t ws_size, hipStream_t stream) {
  const float* x = (const float*)d_in[0];
  const float* cb = (const float*)d_in[1];
  float* out = (float*)d_out;
  float* out_q = out;
  float* out_ind = out + OUT_IND;
  float* out_loss = out + OUT_LOSS;
  float* out_cs = out + OUT_CS;
  float* out_es = out + OUT_ES;

  // Scratch-in-output (all dead before vq_out rewrites out_q; tail fully
  // written by pick/scan/esum so no memset needed):
  u16* Abuf = (u16*)out;                 // bf16 x, 16 MB, dead after mfma
  float* partials = out + P_OFF;         // 4 MB, dead after pick
  int* cnt = (int*)(out + CNT_OFF);
  int* offs = (int*)(out + OFFS_OFF);
  int* woffs = (int*)(out + WOFFS_OFF);
  float* loss_part = out + LP_OFF;
  int* rowlist = (int*)(out + RL_OFF);
  u16* CBb = (u16*)(out + OUT_IND);      // bf16 cb, 4 MB, dead after mfma

  char* w = (char*)d_ws;                 // ws use: 160 KB (proven)
  float* c2 = (float*)w;                 // 32 KB
  int* ind = (int*)(w + (32 << 10));     // 128 KB

  hipMemsetAsync(cnt, 0, KCODES * sizeof(int), stream);
  vq_split_x<<<4096, 256, 0, stream>>>(x, Abuf);
  vq_split_cb_c2<<<1024, 256, 0, stream>>>(cb, CBb, c2);
  vq_mfma<<<256 * NSPLIT, 256, 0, stream>>>(Abuf, CBb, c2, partials);
  vq_pick<<<BN_TOTAL / 4, 256, 0, stream>>>(x, cb, c2, partials, ind, out_ind,
                                            cnt, loss_part);
  vq_scan<<<1, 1024, 0, stream>>>(cnt, offs, woffs, out_cs, loss_part, out_loss);
  vq_scatter<<<BN_TOTAL / 256, 256, 0, stream>>>(ind, woffs, rowlist);
  vq_esum<<<KCODES / 4, 256, 0, stream>>>(x, offs, cnt, rowlist, out_es);
  vq_out<<<BN_TOTAL / 4, 256, 0, stream>>>(cb, ind, out_q);
}

// Round 7
// 361.831 us; speedup vs baseline: 7.6664x; 1.0880x over previous
//
#include <hip/hip_runtime.h>
#include <hip/hip_bf16.h>
#include <math.h>

#define DIM 256
#define KCODES 8192
#define BN_TOTAL 32768
#define NSPLIT 4

// d_out flat f32 layout (reference return order)
#define OUT_IND 8388608
#define OUT_LOSS 8421376
#define OUT_CS 8421377
#define OUT_ES 8429569
#define OUT_TOTAL 10526721

// scratch-in-output offsets (f32 units)
#define ABUF_OFF 0           // x bf16 [32768][256]  = 16 MB, dead after mfma
#define CBB_OFF 4194304      // cb bf16 [8192][256] (swizzled) = 4 MB, dead after mfma
#define PART_OFF OUT_ES      // partials float2[32768][8] = 2 MB, dead after pick

typedef unsigned short u16;
typedef unsigned int u32;
typedef __attribute__((ext_vector_type(8))) short bf16x8;
typedef __attribute__((ext_vector_type(4))) float f32x4;
typedef __attribute__((address_space(1))) const void gvoid_t;
typedef __attribute__((address_space(3))) void lvoid_t;

// ---------------- prep: x -> bf16 hi; cb -> bf16 hi (chunk-swizzled) + c2 ----
__global__ __launch_bounds__(256) void vq_prep(const float* __restrict__ x,
                                               const float* __restrict__ cb,
                                               u16* __restrict__ A,
                                               u16* __restrict__ B,
                                               float* __restrict__ c2,
                                               float* __restrict__ c2m) {
  int b = blockIdx.x;
  if (b < 4096) {
    int g = b * 256 + threadIdx.x;
    int row = g >> 5;
    int d0 = (g & 31) * 8;
    float4 v0 = *(const float4*)(x + (size_t)row * DIM + d0);
    float4 v1 = *(const float4*)(x + (size_t)row * DIM + d0 + 4);
    float vv[8] = {v0.x, v0.y, v0.z, v0.w, v1.x, v1.y, v1.z, v1.w};
    u16 h[8];
#pragma unroll
    for (int i = 0; i < 8; ++i) {
      __hip_bfloat16 bb = __float2bfloat16(vv[i]);
      h[i] = *reinterpret_cast<u16*>(&bb);
    }
    uint4 hv;
    hv.x = (u32)h[0] | ((u32)h[1] << 16); hv.y = (u32)h[2] | ((u32)h[3] << 16);
    hv.z = (u32)h[4] | ((u32)h[5] << 16); hv.w = (u32)h[6] | ((u32)h[7] << 16);
    *(uint4*)(A + (size_t)row * DIM + d0) = hv;
  } else {
    int g = (b - 4096) * 256 + threadIdx.x;
    int code = g >> 5;
    int l5 = g & 31;
    int d0 = l5 * 8;
    float4 v0 = *(const float4*)(cb + (size_t)code * DIM + d0);
    float4 v1 = *(const float4*)(cb + (size_t)code * DIM + d0 + 4);
    float vv[8] = {v0.x, v0.y, v0.z, v0.w, v1.x, v1.y, v1.z, v1.w};
    u16 h[8];
    float s = 0.0f;
#pragma unroll
    for (int i = 0; i < 8; ++i) {
      __hip_bfloat16 bb = __float2bfloat16(vv[i]);
      h[i] = *reinterpret_cast<u16*>(&bb);
      s += vv[i] * vv[i];
    }
    uint4 hv;
    hv.x = (u32)h[0] | ((u32)h[1] << 16); hv.y = (u32)h[2] | ((u32)h[3] << 16);
    hv.z = (u32)h[4] | ((u32)h[5] << 16); hv.w = (u32)h[6] | ((u32)h[7] << 16);
    // chunk swizzle: 16B chunk j of k-group ks stored at j ^ ((code>>1)&3)
    int j = l5 & 3;
    int js = j ^ ((code >> 1) & 3);
    int d0s = ((l5 & ~3) | js) * 8;
    *(uint4*)(B + (size_t)code * DIM + d0s) = hv;
#pragma unroll
    for (int m = 1; m <= 16; m <<= 1) s += __shfl_xor(s, m, 64);  // 32-lane grp
    if (l5 == 0) { c2[code] = s; c2m[code] = s - 256.0f; }
  }
}

// ---------------- main: K=256 bf16 MFMA + packed-key top-2 argmin ----------
// Block: 256 thr = 4 waves over ROWS (wave w: rows w*32..+32, all 128 codes).
// B (x rows) in registers; As (codes) double-buffered 2x8KB, content-swizzled
// so ds_read_b128 is bank-conflict-free (2 lanes/bank quad).
__global__ __launch_bounds__(256, 2)
void vq_mfma(const u16* __restrict__ XB, const u16* __restrict__ CBb,
             const float* __restrict__ c2m, float2* __restrict__ partials) {
  __shared__ __align__(16) u16 As[2][4096];
  const int t = threadIdx.x;
  const int wid = t >> 6;
  const int lane = t & 63;
  const int lhi = lane >> 4, llo = lane & 15;
  const int sl = lhi ^ ((llo >> 1) & 3);   // swizzled 16B-slot for a-reads
  const int rt = blockIdx.x & 255;
  const int s = blockIdx.x >> 8;
  const int row0 = rt * 128;
  const int code0base = s * (KCODES / NSPLIT);

  bf16x8 b[2][8];
#pragma unroll
  for (int n = 0; n < 2; ++n) {
    const u16* bp = XB + (size_t)(row0 + wid * 32 + n * 16 + llo) * DIM + lhi * 8;
#pragma unroll
    for (int ks = 0; ks < 8; ++ks)
      b[n][ks] = *(const bf16x8*)(bp + ks * 32);
  }

  char* AsB = (char*)As;
  const int r0 = t >> 2, c80 = (t & 3) << 3;
  const int r1 = 64 + r0;

  float v1[2], v2[2];
#pragma unroll
  for (int n = 0; n < 2; ++n) { v1[n] = INFINITY; v2[n] = INFINITY; }

  {
    const u16* sa0 = CBb + (size_t)(code0base + r0) * DIM + c80;
    const u16* sa1 = CBb + (size_t)(code0base + r1) * DIM + c80;
    __builtin_amdgcn_global_load_lds((gvoid_t*)sa0, (lvoid_t*)(AsB + (wid << 10)), 16, 0, 0);
    __builtin_amdgcn_global_load_lds((gvoid_t*)sa1, (lvoid_t*)(AsB + 4096 + (wid << 10)), 16, 0, 0);
  }
  __syncthreads();

#pragma unroll 1
  for (int ct = 0; ct < 16; ++ct) {
    const int code0 = code0base + ct * 128;
    f32x4 acc[8][2];
#pragma unroll
    for (int m = 0; m < 8; ++m)
#pragma unroll
      for (int n = 0; n < 2; ++n) acc[m][n] = (f32x4){0.f, 0.f, 0.f, 0.f};

#pragma unroll
    for (int ks = 0; ks < 8; ++ks) {
      const int cur = ks & 1;
      if (!(ct == 15 && ks == 7)) {
        const int nct = (ks == 7) ? ct + 1 : ct;
        const int nks = (ks == 7) ? 0 : ks + 1;
        const u16* sa0 = CBb + (size_t)(code0base + nct * 128 + r0) * DIM + nks * 32 + c80;
        const u16* sa1 = CBb + (size_t)(code0base + nct * 128 + r1) * DIM + nks * 32 + c80;
        char* dst = AsB + ((cur ^ 1) << 13);
        __builtin_amdgcn_global_load_lds((gvoid_t*)sa0, (lvoid_t*)(dst + (wid << 10)), 16, 0, 0);
        __builtin_amdgcn_global_load_lds((gvoid_t*)sa1, (lvoid_t*)(dst + 4096 + (wid << 10)), 16, 0, 0);
      }
      const char* src = AsB + (cur << 13);
      bf16x8 a[8];
#pragma unroll
      for (int m = 0; m < 8; ++m)
        a[m] = *(const bf16x8*)(src + (((m * 16 + llo) << 6) + (sl << 4)));
#pragma unroll
      for (int m = 0; m < 8; ++m) {
        acc[m][0] = __builtin_amdgcn_mfma_f32_16x16x32_bf16(a[m], b[0][ks], acc[m][0], 0, 0, 0);
        acc[m][1] = __builtin_amdgcn_mfma_f32_16x16x32_bf16(a[m], b[1][ks], acc[m][1], 0, 0, 0);
      }
      if (ks == 7) {
        // dist-256 = c2m - 2*dot; pack code into low 13 mantissa bits; top-2
#pragma unroll
        for (int m = 0; m < 8; ++m) {
          int cbase = code0 + m * 16 + lhi * 4;
          float4 cv = *(const float4*)(c2m + cbase);
          float cvv[4] = {cv.x, cv.y, cv.z, cv.w};
#pragma unroll
          for (int n = 0; n < 2; ++n) {
#pragma unroll
            for (int r = 0; r < 4; ++r) {
              float d = fmaf(-2.0f, acc[m][n][r], cvv[r]);
              float key = __uint_as_float((__float_as_uint(d) & ~0x1FFFu) |
                                          (u32)(cbase + r));
              float lo = fminf(key, v1[n]);
              float hi = fmaxf(key, v1[n]);
              v1[n] = lo;
              v2[n] = fminf(v2[n], hi);
            }
          }
        }
      }
      __syncthreads();
    }
  }
  // merge lhi pairs (0<->1, 2<->3): top-2 per 1024-code slice
#pragma unroll
  for (int n = 0; n < 2; ++n) {
    float w1 = __shfl_xor(v1[n], 16, 64);
    float w2 = __shfl_xor(v2[n], 16, 64);
    float m1 = fminf(v1[n], w1);
    float m2 = fminf(fmaxf(v1[n], w1), fminf(v2[n], w2));
    if ((lhi & 1) == 0) {
      int row = row0 + wid * 32 + n * 16 + llo;
      int gslot = lhi >> 1;
      partials[(size_t)row * 8 + s * 2 + gslot] = make_float2(m1, m2);
    }
  }
}

// ---- pick: 16 cands -> top-4 -> exact rescore -> ind/out_ind/out_q/hist ----
__global__ __launch_bounds__(256)
void vq_pick(const float* __restrict__ x, const float* __restrict__ cb,
             const float* __restrict__ c2g, const float2* __restrict__ partials,
             int* __restrict__ ind, float* __restrict__ out_ind,
             float* __restrict__ out_q, int* __restrict__ cnt,
             float* __restrict__ loss_part) {
  __shared__ float lsm[4];
  int wid = threadIdx.x >> 6, lane = threadIdx.x & 63;
  int row = blockIdx.x * 4 + wid;
  float cv = INFINITY, cv2 = INFINITY;
  if (lane < 8) {
    float2 p = partials[(size_t)row * 8 + lane];
    cv = p.x; cv2 = p.y;
  }
  int cand[4];
#pragma unroll
  for (int rsel = 0; rsel < 4; ++rsel) {
    float bv = cv;
#pragma unroll
    for (int mask = 1; mask < 64; mask <<= 1)
      bv = fminf(bv, __shfl_xor(bv, mask, 64));
    cand[rsel] = (int)(__float_as_uint(bv) & 8191u);
    if (cv == bv) { cv = cv2; cv2 = INFINITY; }
  }
  const float4 xv = *(const float4*)(x + (size_t)row * DIM + lane * 4);
  float4 q0 = *(const float4*)(cb + (size_t)cand[0] * DIM + lane * 4);
  float4 q1 = *(const float4*)(cb + (size_t)cand[1] * DIM + lane * 4);
  float4 q2 = *(const float4*)(cb + (size_t)cand[2] * DIM + lane * 4);
  float4 q3 = *(const float4*)(cb + (size_t)cand[3] * DIM + lane * 4);
  float d0 = xv.x * q0.x + xv.y * q0.y + xv.z * q0.z + xv.w * q0.w;
  float d1 = xv.x * q1.x + xv.y * q1.y + xv.z * q1.z + xv.w * q1.w;
  float d2 = xv.x * q2.x + xv.y * q2.y + xv.z * q2.z + xv.w * q2.w;
  float d3 = xv.x * q3.x + xv.y * q3.y + xv.z * q3.z + xv.w * q3.w;
  float x2 = xv.x * xv.x + xv.y * xv.y + xv.z * xv.z + xv.w * xv.w;
#pragma unroll
  for (int mask = 1; mask < 64; mask <<= 1) {
    d0 += __shfl_xor(d0, mask, 64);
    d1 += __shfl_xor(d1, mask, 64);
    d2 += __shfl_xor(d2, mask, 64);
    d3 += __shfl_xor(d3, mask, 64);
    x2 += __shfl_xor(x2, mask, 64);
  }
  float e0 = fmaf(-2.0f, d0, c2g[cand[0]]);
  float e1 = fmaf(-2.0f, d1, c2g[cand[1]]);
  float e2 = fmaf(-2.0f, d2, c2g[cand[2]]);
  float e3 = fmaf(-2.0f, d3, c2g[cand[3]]);
  float best = e0; int bk = cand[0];
  if (e1 < best || (e1 == best && cand[1] < bk)) { best = e1; bk = cand[1]; }
  if (e2 < best || (e2 == best && cand[2] < bk)) { best = e2; bk = cand[2]; }
  if (e3 < best || (e3 == best && cand[3] < bk)) { best = e3; bk = cand[3]; }
  // fused out_q write: gather the winning codebook row (L2-resident)
  float4 q = *(const float4*)(cb + (size_t)bk * DIM + lane * 4);
  *(float4*)(out_q + (size_t)row * DIM + lane * 4) = q;
  if (lane == 0) {
    ind[row] = bk;
    out_ind[row] = (float)bk;
    atomicAdd(cnt + bk, 1);
    lsm[wid] = x2 + best;   // == ||q - x||^2 (exact identity)
  }
  __syncthreads();
  if (threadIdx.x == 0)
    loss_part[blockIdx.x] = lsm[0] + lsm[1] + lsm[2] + lsm[3];
}

// ---- scan: exclusive scan cnt -> offs/woffs; out_cs; reduce loss ----
__global__ __launch_bounds__(1024)
void vq_scan(const int* __restrict__ cnt, int* __restrict__ offs,
             int* __restrict__ woffs, float* __restrict__ out_cs,
             const float* __restrict__ loss_part, float* __restrict__ out_loss) {
  __shared__ int ssum[1024];
  __shared__ float sls[1024];
  int tid = threadIdx.x;
  int c[8], loc[8];
  int s = 0;
#pragma unroll
  for (int j = 0; j < 8; ++j) {
    c[j] = cnt[tid * 8 + j];
    loc[j] = s;
    s += c[j];
  }
  ssum[tid] = s;
  float ls = 0.0f;
#pragma unroll
  for (int j = 0; j < 8; ++j) ls += loss_part[tid * 8 + j];
  sls[tid] = ls;
  __syncthreads();
  for (int off = 1; off < 1024; off <<= 1) {
    int v = (tid >= off) ? ssum[tid - off] : 0;
    __syncthreads();
    ssum[tid] += v;
    __syncthreads();
  }
  int base = (tid > 0) ? ssum[tid - 1] : 0;
#pragma unroll
  for (int j = 0; j < 8; ++j) {
    int o = base + loc[j];
    offs[tid * 8 + j] = o;
    woffs[tid * 8 + j] = o;
    out_cs[tid * 8 + j] = (float)c[j];
  }
  for (int off = 512; off >= 1; off >>= 1) {
    if (tid < off) sls[tid] += sls[tid + off];
    __syncthreads();
  }
  if (tid == 0) *out_loss = sls[0] * (1.0f / 8388608.0f);
}

// ---- scatter: build rowlist grouped by code ----
__global__ __launch_bounds__(256)
void vq_scatter(const int* __restrict__ ind, int* __restrict__ woffs,
                int* __restrict__ rowlist) {
  int row = blockIdx.x * 256 + threadIdx.x;
  int k = ind[row];
  int pos = atomicAdd(woffs + k, 1);
  rowlist[pos] = row;
}

// ---- esum: one wave per code, register-accumulated segment sum ----
__global__ __launch_bounds__(256)
void vq_esum(const float* __restrict__ x, const int* __restrict__ offs,
             const int* __restrict__ cnt, const int* __restrict__ rowlist,
             float* __restrict__ out_es) {
  int wid = threadIdx.x >> 6, lane = threadIdx.x & 63;
  int k = blockIdx.x * 4 + wid;
  int start = offs[k], n = cnt[k];
  float4 acc = {0.f, 0.f, 0.f, 0.f};
  for (int base = 0; base < n; base += 64) {
    int r = (base + lane < n) ? rowlist[start + base + lane] : 0;
    int lim = min(64, n - base);
    for (int j = 0; j < lim; ++j) {
      int row = __shfl(r, j, 64);
      float4 xv = *(const float4*)(x + (size_t)row * DIM + lane * 4);
      acc.x += xv.x; acc.y += xv.y; acc.z += xv.z; acc.w += xv.w;
    }
  }
  *(float4*)(out_es + (size_t)k * DIM + lane * 4) = acc;
}

extern "C" void kernel_launch(void* const* d_in, const int* in_sizes, int n_in,
                              void* d_out, int out_size, void* d_ws,
                              size_t ws_size, hipStream_t stream) {
  const float* x = (const float*)d_in[0];
  const float* cb = (const float*)d_in[1];
  float* out = (float*)d_out;
  float* out_q = out;
  float* out_ind = out + OUT_IND;
  float* out_loss = out + OUT_LOSS;
  float* out_cs = out + OUT_CS;
  float* out_es = out + OUT_ES;

  // Scratch-in-output:
  //  Abuf = out[0..4M), CBb = out[4M..6.3M)  -- both dead after vq_mfma,
  //      and vq_pick rewrites all of out_q afterwards.
  //  partials = out[OUT_ES..+512K floats)    -- dead after vq_pick; vq_esum
  //      then rewrites all of out_es.
  u16* Abuf = (u16*)(out + ABUF_OFF);
  u16* CBb = (u16*)(out + CBB_OFF);
  float2* partials = (float2*)(out + PART_OFF);

  // ws layout (448 KB; >= 2.16 MB proven available in round 1)
  char* w = (char*)d_ws;
  float* c2 = (float*)w;                          // 32 KB
  int* ind = (int*)(w + (32 << 10));              // 128 KB
  float* c2m = (float*)(w + (160 << 10));         // 32 KB
  int* cnt = (int*)(w + (192 << 10));             // 32 KB
  int* offs = (int*)(w + (224 << 10));            // 32 KB
  int* woffs = (int*)(w + (256 << 10));           // 32 KB
  float* loss_part = (float*)(w + (288 << 10));   // 32 KB
  int* rowlist = (int*)(w + (320 << 10));         // 128 KB

  hipMemsetAsync(cnt, 0, KCODES * sizeof(int), stream);
  vq_prep<<<5120, 256, 0, stream>>>(x, cb, Abuf, CBb, c2, c2m);
  vq_mfma<<<256 * NSPLIT, 256, 0, stream>>>(Abuf, CBb, c2m, partials);
  vq_pick<<<BN_TOTAL / 4, 256, 0, stream>>>(x, cb, c2, partials, ind, out_ind,
                                            out_q, cnt, loss_part);
  vq_scan<<<1, 1024, 0, stream>>>(cnt, offs, woffs, out_cs, loss_part, out_loss);
  vq_scatter<<<BN_TOTAL / 256, 256, 0, stream>>>(ind, woffs, rowlist);
  vq_esum<<<KCODES / 4, 256, 0, stream>>>(x, offs, cnt, rowlist, out_es);
}